// Round 1
// baseline (190.450 us; speedup 1.0000x reference)
//
#include <hip/hip_runtime.h>
#include <stdint.h>

typedef short bf16x8 __attribute__((ext_vector_type(8)));
typedef float f32x4 __attribute__((ext_vector_type(4)));

#define NROWS 16384
#define K1DIM 256
#define N1DIM 2048
#define N2DIM 96

#define GLD16(g, l) __builtin_amdgcn_global_load_lds( \
    (const __attribute__((address_space(1))) uint32_t*)(g), \
    (__attribute__((address_space(3))) uint32_t*)(l), 16, 0, 0)

__device__ __forceinline__ ushort f2bf(float x) {
  union { float f; uint32_t u; } c; c.f = x;
  uint32_t u = c.u;
  return (ushort)((u + 0x7FFFu + ((u >> 16) & 1u)) >> 16);
}

// ---------------- K0: convert inputs to bf16 (x2, Wl1^T, W2sel^T) ----------
__global__ __launch_bounds__(256) void k0_convert(
    const float* __restrict__ bd, const float* __restrict__ Wl1,
    const float* __restrict__ Wl2, ushort* __restrict__ x2bf,
    ushort* __restrict__ wl1t, ushort* __restrict__ w2t) {
  int i = blockIdx.x * 256 + threadIdx.x;
  if (i < NROWS * 256) x2bf[i] = f2bf(bd[i]);
  if (i < 2048 * 256) {  // wl1t[n][k] = Wl1[k][n]
    int n = i >> 8, k = i & 255;
    wl1t[i] = f2bf(Wl1[k * 2048 + n]);
  }
  if (i < 96 * 2048) {   // w2t[j][k] = Wl2[k][colmap(j)]; j<48 -> leaf0, else leaf31
    int j = i >> 11, k = i & 2047;
    int col = (j < 48) ? j : (1440 + j);  // 1488 + (j-48)
    w2t[i] = f2bf(Wl2[k * 1536 + col]);
  }
}

// ---------------- K1: fp32 branch -> router bit ----------------------------
// score(b) = relu(main_b @ Wb1 + bb1) . (Wb2[:,1]-Wb2[:,0]) + (bb2[1]-bb2[0])
// router = score >= 0 ? 1 (leaf31) : 0 (leaf0)
__global__ __launch_bounds__(256) void k1_branch(
    const float* __restrict__ bd, const float* __restrict__ Wb1,
    const float* __restrict__ Wb2, const float* __restrict__ bb1,
    const float* __restrict__ bb2, int* __restrict__ router) {
  __shared__ __align__(16) float xs[128 * 64];   // [m][r], stride 64
  __shared__ __align__(16) float wsh[128 * 64];  // [m][j], stride 64
  const int t = threadIdx.x;
  const int ln = t & 63, wv = t >> 6;
  const int rb = blockIdx.x * 64;

  // stage xs: thread (r = t&63, c0 = t>>6), 8 float4 column-chunks
  {
    int r = t & 63, c0 = t >> 6;
#pragma unroll
    for (int p = 0; p < 8; p++) {
      int c = c0 + p * 4;  // 0..31 float4s -> m = c*4..c*4+3
      float4 v = *(const float4*)(bd + (size_t)(rb + r) * 256 + c * 4);
      xs[(c * 4 + 0) * 64 + r] = v.x;
      xs[(c * 4 + 1) * 64 + r] = v.y;
      xs[(c * 4 + 2) * 64 + r] = v.z;
      xs[(c * 4 + 3) * 64 + r] = v.w;
    }
  }

  const int jj = ln & 31;
  const int rowbase = (wv << 4) + ((ln >> 5) << 3);  // this lane's 8 rows (block-rel)
  float score[8];
#pragma unroll
  for (int i = 0; i < 8; i++) score[i] = 0.f;

  for (int jc = 0; jc < 8; jc++) {
    int j0 = jc * 64;
    __syncthreads();  // previous chunk fully consumed (also covers xs on first iter)
    // stage wsh[m][jj] = Wb1[m][j0+jj]
    {
      int q4 = (t & 15) * 4;
      int mb = t >> 4;  // 0..15
#pragma unroll
      for (int p = 0; p < 8; p++) {
        int m = mb + p * 16;
        float4 v = *(const float4*)(Wb1 + (size_t)m * 512 + j0 + q4);
        *(float4*)(&wsh[m * 64 + q4]) = v;
      }
    }
    __syncthreads();

    float b1A = bb1[j0 + jj];
    float b1B = bb1[j0 + 32 + jj];
    float aA[8], aB[8];
#pragma unroll
    for (int i = 0; i < 8; i++) { aA[i] = b1A; aB[i] = b1B; }

#pragma unroll 4
    for (int m = 0; m < 128; m++) {
      float wA = wsh[(m << 6) + jj];
      float wB = wsh[(m << 6) + 32 + jj];
      const float* xp = &xs[(m << 6) + rowbase];
      float4 x0 = *(const float4*)(xp);
      float4 x1 = *(const float4*)(xp + 4);
      float xv[8] = {x0.x, x0.y, x0.z, x0.w, x1.x, x1.y, x1.z, x1.w};
#pragma unroll
      for (int i = 0; i < 8; i++) {
        aA[i] = fmaf(wA, xv[i], aA[i]);
        aB[i] = fmaf(wB, xv[i], aB[i]);
      }
    }
    int jA = j0 + jj, jB = jA + 32;
    float wdA = Wb2[jA * 2 + 1] - Wb2[jA * 2];
    float wdB = Wb2[jB * 2 + 1] - Wb2[jB * 2];
#pragma unroll
    for (int i = 0; i < 8; i++)
      score[i] += fmaxf(aA[i], 0.f) * wdA + fmaxf(aB[i], 0.f) * wdB;
  }

  // reduce across the 32 lanes of each half-wave
#pragma unroll
  for (int off = 1; off <= 16; off <<= 1) {
#pragma unroll
    for (int i = 0; i < 8; i++) score[i] += __shfl_xor(score[i], off);
  }
  float c = bb2[1] - bb2[0];
  if ((ln & 31) == 0) {
    int rbase = rb + rowbase;
#pragma unroll
    for (int i = 0; i < 8; i++)
      router[rbase + i] = (score[i] + c >= 0.f) ? 1 : 0;
  }
}

// ---------------- K2a: GEMM1  hl = relu(x2 @ Wl1 + bl1)  (bf16 MFMA) -------
__global__ __launch_bounds__(256) void k2_gemm1(
    const ushort* __restrict__ A, const ushort* __restrict__ BT,
    const float* __restrict__ bl1, ushort* __restrict__ hl) {
  __shared__ __align__(1024) ushort As[128 * 64];  // [r][64k] row-major
  __shared__ __align__(1024) ushort Bs[128 * 64];
  const int t = threadIdx.x, ln = t & 63, wv = t >> 6;
  const int m0 = blockIdx.y << 7;
  const int n0 = blockIdx.x << 7;
  const int wm = (wv >> 1) << 6, wn = (wv & 1) << 6;
  const int rsub = ln >> 3, kc8 = ln & 7;
  const int q = ln >> 4, rr = ln & 15;

  f32x4 acc[4][4] = {};

  for (int k0 = 0; k0 < K1DIM; k0 += 64) {
#pragma unroll
    for (int i = 0; i < 4; i++) {
      int inst = (wv << 2) + i;
      int row = (inst << 3) + rsub;
      GLD16(A + (size_t)(m0 + row) * K1DIM + k0 + (kc8 << 3), As + (inst << 9));
      GLD16(BT + (size_t)(n0 + row) * K1DIM + k0 + (kc8 << 3), Bs + (inst << 9));
    }
    __syncthreads();
#pragma unroll
    for (int kk = 0; kk < 2; kk++) {
      int kb = ((kk << 2) + q) << 3;
      bf16x8 af[4], bfr[4];
#pragma unroll
      for (int mi = 0; mi < 4; mi++)
        af[mi] = *(const bf16x8*)(As + (((wm + (mi << 4) + rr)) << 6) + kb);
#pragma unroll
      for (int ni = 0; ni < 4; ni++)
        bfr[ni] = *(const bf16x8*)(Bs + (((wn + (ni << 4) + rr)) << 6) + kb);
#pragma unroll
      for (int mi = 0; mi < 4; mi++)
#pragma unroll
        for (int ni = 0; ni < 4; ni++)
          acc[mi][ni] = __builtin_amdgcn_mfma_f32_16x16x32_bf16(
              af[mi], bfr[ni], acc[mi][ni], 0, 0, 0);
    }
    __syncthreads();
  }

#pragma unroll
  for (int ni = 0; ni < 4; ni++) {
    int col = n0 + wn + (ni << 4) + rr;
    float bias = bl1[col];
#pragma unroll
    for (int mi = 0; mi < 4; mi++) {
      int rowb = m0 + wm + (mi << 4) + (q << 2);
      f32x4 a = acc[mi][ni];
#pragma unroll
      for (int v = 0; v < 4; v++) {
        float val = fmaxf(a[v] + bias, 0.f);
        hl[(size_t)(rowb + v) * N1DIM + col] = f2bf(val);
      }
    }
  }
}

// ---------------- K2b: GEMM2 both-leaf partials (split-K) ------------------
__global__ __launch_bounds__(256) void k2b_gemm2(
    const ushort* __restrict__ hl, const ushort* __restrict__ w2t,
    float* __restrict__ P) {
  __shared__ __align__(1024) ushort As[64 * 64];
  __shared__ __align__(1024) ushort Bs[96 * 64];
  const int t = threadIdx.x, ln = t & 63, wv = t >> 6;
  const int ks = blockIdx.x;        // split-K: 0,1
  const int rb = blockIdx.y << 6;   // 64-row block
  const int rsub = ln >> 3, kc8 = ln & 7;
  const int q = ln >> 4, rr = ln & 15;
  float* Pout = P + (size_t)ks * NROWS * N2DIM;
  const int kbase = ks << 10;

  f32x4 acc[6] = {};

  for (int k0 = 0; k0 < 1024; k0 += 64) {
    int kg = kbase + k0;
#pragma unroll
    for (int i = 0; i < 2; i++) {
      int inst = (wv << 1) + i;
      int row = (inst << 3) + rsub;
      GLD16(hl + (size_t)(rb + row) * N1DIM + kg + (kc8 << 3), As + (inst << 9));
    }
#pragma unroll
    for (int i = 0; i < 3; i++) {
      int inst = wv * 3 + i;
      int row = (inst << 3) + rsub;
      GLD16(w2t + (size_t)row * N1DIM + kg + (kc8 << 3), Bs + (inst << 9));
    }
    __syncthreads();
#pragma unroll
    for (int kk = 0; kk < 2; kk++) {
      int kb = ((kk << 2) + q) << 3;
      bf16x8 af = *(const bf16x8*)(As + (((wv << 4) + rr) << 6) + kb);
#pragma unroll
      for (int ni = 0; ni < 6; ni++) {
        bf16x8 bfr = *(const bf16x8*)(Bs + (((ni << 4) + rr) << 6) + kb);
        acc[ni] = __builtin_amdgcn_mfma_f32_16x16x32_bf16(af, bfr, acc[ni], 0, 0, 0);
      }
    }
    __syncthreads();
  }

#pragma unroll
  for (int ni = 0; ni < 6; ni++) {
#pragma unroll
    for (int v = 0; v < 4; v++) {
      int row = rb + (wv << 4) + (q << 2) + v;
      int col = (ni << 4) + rr;
      Pout[(size_t)row * N2DIM + col] = acc[ni][v];
    }
  }
}

// ---------------- K3: sum partials, select leaf, add bias ------------------
__global__ __launch_bounds__(256) void k3_select(
    const float* __restrict__ P0, const float* __restrict__ P1,
    const float* __restrict__ bl2, const int* __restrict__ router,
    float* __restrict__ out) {
  int t = blockIdx.x * 256 + threadIdx.x;  // < 16384*12
  int b = t / 12, i4 = (t % 12) * 4;
  int sel = router[b];
  int cb = sel ? 48 : 0;
  int bb = sel ? 1488 : 0;
  float4 p0 = *(const float4*)(P0 + (size_t)b * N2DIM + cb + i4);
  float4 p1 = *(const float4*)(P1 + (size_t)b * N2DIM + cb + i4);
  float4 bz = *(const float4*)(bl2 + bb + i4);
  float4 r;
  r.x = p0.x + p1.x + bz.x;
  r.y = p0.y + p1.y + bz.y;
  r.z = p0.z + p1.z + bz.z;
  r.w = p0.w + p1.w + bz.w;
  *(float4*)(out + (size_t)b * 48 + i4) = r;
}

extern "C" void kernel_launch(void* const* d_in, const int* in_sizes, int n_in,
                              void* d_out, int out_size, void* d_ws, size_t ws_size,
                              hipStream_t stream) {
  const float* bd  = (const float*)d_in[0];
  const float* Wl1 = (const float*)d_in[1];
  const float* bl1 = (const float*)d_in[2];
  const float* Wl2 = (const float*)d_in[3];
  const float* bl2 = (const float*)d_in[4];
  const float* Wb1 = (const float*)d_in[5];
  const float* bb1 = (const float*)d_in[6];
  const float* Wb2 = (const float*)d_in[7];
  const float* bb2 = (const float*)d_in[8];

  char* ws = (char*)d_ws;
  ushort* x2bf  = (ushort*)(ws);                  // 16384*256*2  = 8,388,608
  ushort* wl1t  = (ushort*)(ws + 8388608);        // 2048*256*2   = 1,048,576
  ushort* w2t   = (ushort*)(ws + 9437184);        // 96*2048*2    =   393,216
  ushort* hl    = (ushort*)(ws + 9830400);        // 16384*2048*2 = 67,108,864
  float*  P     = (float*)(ws + 76939264);        // 2*16384*96*4 = 12,582,912
  int*    router= (int*)(ws + 89522176);          // 16384*4
  float*  outp  = (float*)d_out;

  k0_convert<<<dim3(16384), dim3(256), 0, stream>>>(bd, Wl1, Wl2, x2bf, wl1t, w2t);
  k1_branch<<<dim3(256), dim3(256), 0, stream>>>(bd, Wb1, Wb2, bb1, bb2, router);
  k2_gemm1<<<dim3(16, 128), dim3(256), 0, stream>>>(x2bf, wl1t, bl1, hl);
  k2b_gemm2<<<dim3(2, 256), dim3(256), 0, stream>>>(hl, w2t, P);
  k3_select<<<dim3(768), dim3(256), 0, stream>>>(P, P + (size_t)NROWS * N2DIM, bl2,
                                                 router, outp);
}

// Round 2
// 184.153 us; speedup vs baseline: 1.0342x; 1.0342x over previous
//
#include <hip/hip_runtime.h>
#include <stdint.h>

typedef short bf16x8 __attribute__((ext_vector_type(8)));
typedef float f32x4 __attribute__((ext_vector_type(4)));

#define NROWS 16384
#define K1DIM 256
#define N1DIM 2048
#define N2DIM 96
#define MARGIN 0.03f

#define GLD16(g, l) __builtin_amdgcn_global_load_lds( \
    (const __attribute__((address_space(1))) uint32_t*)(g), \
    (__attribute__((address_space(3))) uint32_t*)(l), 16, 0, 0)

__device__ __forceinline__ ushort f2bf(float x) {
  union { float f; uint32_t u; } c; c.f = x;
  uint32_t u = c.u;
  return (ushort)((u + 0x7FFFu + ((u >> 16) & 1u)) >> 16);
}

// ---------------- K0: convert inputs to bf16 (x2, Wl1^T, W2sel^T, Wb1^T) ---
__global__ __launch_bounds__(256) void k0_convert(
    const float* __restrict__ bd, const float* __restrict__ Wl1,
    const float* __restrict__ Wl2, const float* __restrict__ Wb1,
    ushort* __restrict__ x2bf, ushort* __restrict__ wl1t,
    ushort* __restrict__ w2t, ushort* __restrict__ wb1t) {
  int i = blockIdx.x * 256 + threadIdx.x;
  if (i < NROWS * 256) x2bf[i] = f2bf(bd[i]);
  if (i < 2048 * 256) {  // wl1t[n][k] = Wl1[k][n]
    int n = i >> 8, k = i & 255;
    wl1t[i] = f2bf(Wl1[k * 2048 + n]);
  }
  if (i < 96 * 2048) {   // w2t[j][k] = Wl2[k][colmap(j)]; j<48 -> leaf0, else leaf31
    int j = i >> 11, k = i & 2047;
    int col = (j < 48) ? j : (1440 + j);  // 1488 + (j-48)
    w2t[i] = f2bf(Wl2[k * 1536 + col]);
  }
  if (i < 512 * 128) {   // wb1t[j][m] = Wb1[m][j]
    int j = i >> 7, m = i & 127;
    wb1t[i] = f2bf(Wb1[m * 512 + j]);
  }
}

// ---------------- K1a: branch scores via bf16 MFMA -------------------------
// part[(nb*2 + wnhalf)*16384 + row] = sum_{cols in half} relu(h)*wd
__global__ __launch_bounds__(256) void k1a_score(
    const ushort* __restrict__ x2bf, const ushort* __restrict__ wb1t,
    const float* __restrict__ bb1, const float* __restrict__ Wb2,
    float* __restrict__ part) {
  __shared__ __align__(1024) ushort As[128 * 64];
  __shared__ __align__(1024) ushort Bs[128 * 64];
  const int t = threadIdx.x, ln = t & 63, wv = t >> 6;
  const int m0 = blockIdx.y << 7;  // 128 row-blocks
  const int n0 = blockIdx.x << 7;  // 4 col-blocks
  const int wm = (wv >> 1) << 6, wn = (wv & 1) << 6;
  const int rsub = ln >> 3, kc8 = ln & 7;
  const int q = ln >> 4, rr = ln & 15;

  f32x4 acc[4][4] = {};

  for (int k0 = 0; k0 < 128; k0 += 64) {
#pragma unroll
    for (int i = 0; i < 4; i++) {
      int inst = (wv << 2) + i;
      int row = (inst << 3) + rsub;
      GLD16(x2bf + (size_t)(m0 + row) * 256 + k0 + (kc8 << 3), As + (inst << 9));
      GLD16(wb1t + (size_t)(n0 + row) * 128 + k0 + (kc8 << 3), Bs + (inst << 9));
    }
    __syncthreads();
#pragma unroll
    for (int kk = 0; kk < 2; kk++) {
      int kb = ((kk << 2) + q) << 3;
      bf16x8 af[4], bfr[4];
#pragma unroll
      for (int mi = 0; mi < 4; mi++)
        af[mi] = *(const bf16x8*)(As + (((wm + (mi << 4) + rr)) << 6) + kb);
#pragma unroll
      for (int ni = 0; ni < 4; ni++)
        bfr[ni] = *(const bf16x8*)(Bs + (((wn + (ni << 4) + rr)) << 6) + kb);
#pragma unroll
      for (int mi = 0; mi < 4; mi++)
#pragma unroll
        for (int ni = 0; ni < 4; ni++)
          acc[mi][ni] = __builtin_amdgcn_mfma_f32_16x16x32_bf16(
              af[mi], bfr[ni], acc[mi][ni], 0, 0, 0);
    }
    __syncthreads();
  }

  // epilogue: bias + relu + dot with wd, reduce over this lane's 4 cols
  float s4[4][4] = {};  // [mi][v]
#pragma unroll
  for (int ni = 0; ni < 4; ni++) {
    int col = n0 + wn + (ni << 4) + rr;
    float bias = bb1[col];
    float wdv = Wb2[col * 2 + 1] - Wb2[col * 2];
#pragma unroll
    for (int mi = 0; mi < 4; mi++) {
      f32x4 a = acc[mi][ni];
#pragma unroll
      for (int v = 0; v < 4; v++)
        s4[mi][v] += fmaxf(a[v] + bias, 0.f) * wdv;
    }
  }
  // reduce across the 16 lanes (rr) sharing the same rows
#pragma unroll
  for (int off = 1; off <= 8; off <<= 1)
#pragma unroll
    for (int mi = 0; mi < 4; mi++)
#pragma unroll
      for (int v = 0; v < 4; v++)
        s4[mi][v] += __shfl_xor(s4[mi][v], off);

  if (rr == 0) {
    float* dst = part + (size_t)(blockIdx.x * 2 + (wv & 1)) * NROWS +
                 m0 + wm + (q << 2);
#pragma unroll
    for (int mi = 0; mi < 4; mi++) {
      float4 v4 = make_float4(s4[mi][0], s4[mi][1], s4[mi][2], s4[mi][3]);
      *(float4*)(dst + (mi << 4)) = v4;
    }
  }
}

// ---------------- K1b: sum partials, classify, compact marginal rows -------
__global__ __launch_bounds__(256) void k1b_classify(
    const float* __restrict__ part, const float* __restrict__ bb2,
    int* __restrict__ router, int* __restrict__ list, int* __restrict__ counter) {
  int t = blockIdx.x * 256 + threadIdx.x;
  float s = bb2[1] - bb2[0];
#pragma unroll
  for (int i = 0; i < 8; i++) s += part[i * NROWS + t];
  router[t] = (s >= 0.f) ? 1 : 0;
  if (fabsf(s) < MARGIN) {
    int idx = atomicAdd(counter, 1);
    list[idx] = t;
  }
}

// ---------------- K1c: exact fp32 recheck of marginal rows -----------------
__global__ __launch_bounds__(256) void k1c_recheck(
    const float* __restrict__ bd, const float* __restrict__ Wb1,
    const float* __restrict__ Wb2, const float* __restrict__ bb1,
    const float* __restrict__ bb2, const int* __restrict__ list,
    const int* __restrict__ counter, int* __restrict__ router) {
  const int ln = threadIdx.x & 63;
  const int wid = (blockIdx.x * 256 + threadIdx.x) >> 6;  // 0..511
  const int count = *counter;
  const float c = bb2[1] - bb2[0];

  for (int base = wid * 4; base < count; base += 512 * 4) {
    int rows[4];
#pragma unroll
    for (int r = 0; r < 4; r++) {
      int idx = base + r;
      rows[r] = list[(idx < count) ? idx : base];
    }
    float acc[4][8];
#pragma unroll
    for (int r = 0; r < 4; r++)
#pragma unroll
      for (int u = 0; u < 8; u++) acc[r][u] = 0.f;

    for (int m = 0; m < 128; m++) {
      float w[8];
#pragma unroll
      for (int u = 0; u < 8; u++) w[u] = Wb1[m * 512 + (u << 6) + ln];
#pragma unroll
      for (int r = 0; r < 4; r++) {
        float x = bd[(size_t)rows[r] * 256 + m];
#pragma unroll
        for (int u = 0; u < 8; u++) acc[r][u] = fmaf(x, w[u], acc[r][u]);
      }
    }
    float sc[4];
#pragma unroll
    for (int r = 0; r < 4; r++) {
      float s = 0.f;
#pragma unroll
      for (int u = 0; u < 8; u++) {
        int j = (u << 6) + ln;
        float wd = Wb2[j * 2 + 1] - Wb2[j * 2];
        s += fmaxf(acc[r][u] + bb1[j], 0.f) * wd;
      }
#pragma unroll
      for (int off = 1; off <= 32; off <<= 1) s += __shfl_xor(s, off);
      sc[r] = s + c;
    }
    if (ln == 0) {
#pragma unroll
      for (int r = 0; r < 4; r++)
        if (base + r < count) router[rows[r]] = (sc[r] >= 0.f) ? 1 : 0;
    }
  }
}

// ---------------- K2a: GEMM1  hl = relu(x2 @ Wl1 + bl1)  (bf16 MFMA) -------
__global__ __launch_bounds__(256) void k2_gemm1(
    const ushort* __restrict__ A, const ushort* __restrict__ BT,
    const float* __restrict__ bl1, ushort* __restrict__ hl) {
  __shared__ __align__(1024) ushort As[128 * 64];  // [r][64k] row-major
  __shared__ __align__(1024) ushort Bs[128 * 64];
  const int t = threadIdx.x, ln = t & 63, wv = t >> 6;
  const int m0 = blockIdx.y << 7;
  const int n0 = blockIdx.x << 7;
  const int wm = (wv >> 1) << 6, wn = (wv & 1) << 6;
  const int rsub = ln >> 3, kc8 = ln & 7;
  const int q = ln >> 4, rr = ln & 15;

  f32x4 acc[4][4] = {};

  for (int k0 = 0; k0 < K1DIM; k0 += 64) {
#pragma unroll
    for (int i = 0; i < 4; i++) {
      int inst = (wv << 2) + i;
      int row = (inst << 3) + rsub;
      GLD16(A + (size_t)(m0 + row) * K1DIM + k0 + (kc8 << 3), As + (inst << 9));
      GLD16(BT + (size_t)(n0 + row) * K1DIM + k0 + (kc8 << 3), Bs + (inst << 9));
    }
    __syncthreads();
#pragma unroll
    for (int kk = 0; kk < 2; kk++) {
      int kb = ((kk << 2) + q) << 3;
      bf16x8 af[4], bfr[4];
#pragma unroll
      for (int mi = 0; mi < 4; mi++)
        af[mi] = *(const bf16x8*)(As + (((wm + (mi << 4) + rr)) << 6) + kb);
#pragma unroll
      for (int ni = 0; ni < 4; ni++)
        bfr[ni] = *(const bf16x8*)(Bs + (((wn + (ni << 4) + rr)) << 6) + kb);
#pragma unroll
      for (int mi = 0; mi < 4; mi++)
#pragma unroll
        for (int ni = 0; ni < 4; ni++)
          acc[mi][ni] = __builtin_amdgcn_mfma_f32_16x16x32_bf16(
              af[mi], bfr[ni], acc[mi][ni], 0, 0, 0);
    }
    __syncthreads();
  }

#pragma unroll
  for (int ni = 0; ni < 4; ni++) {
    int col = n0 + wn + (ni << 4) + rr;
    float bias = bl1[col];
#pragma unroll
    for (int mi = 0; mi < 4; mi++) {
      int rowb = m0 + wm + (mi << 4) + (q << 2);
      f32x4 a = acc[mi][ni];
#pragma unroll
      for (int v = 0; v < 4; v++) {
        float val = fmaxf(a[v] + bias, 0.f);
        hl[(size_t)(rowb + v) * N1DIM + col] = f2bf(val);
      }
    }
  }
}

// ---------------- K2b: GEMM2 both-leaf partials (split-K) ------------------
__global__ __launch_bounds__(256) void k2b_gemm2(
    const ushort* __restrict__ hl, const ushort* __restrict__ w2t,
    float* __restrict__ P) {
  __shared__ __align__(1024) ushort As[64 * 64];
  __shared__ __align__(1024) ushort Bs[96 * 64];
  const int t = threadIdx.x, ln = t & 63, wv = t >> 6;
  const int ks = blockIdx.x;        // split-K: 0,1
  const int rb = blockIdx.y << 6;   // 64-row block
  const int rsub = ln >> 3, kc8 = ln & 7;
  const int q = ln >> 4, rr = ln & 15;
  float* Pout = P + (size_t)ks * NROWS * N2DIM;
  const int kbase = ks << 10;

  f32x4 acc[6] = {};

  for (int k0 = 0; k0 < 1024; k0 += 64) {
    int kg = kbase + k0;
#pragma unroll
    for (int i = 0; i < 2; i++) {
      int inst = (wv << 1) + i;
      int row = (inst << 3) + rsub;
      GLD16(hl + (size_t)(rb + row) * N1DIM + kg + (kc8 << 3), As + (inst << 9));
    }
#pragma unroll
    for (int i = 0; i < 3; i++) {
      int inst = wv * 3 + i;
      int row = (inst << 3) + rsub;
      GLD16(w2t + (size_t)row * N1DIM + kg + (kc8 << 3), Bs + (inst << 9));
    }
    __syncthreads();
#pragma unroll
    for (int kk = 0; kk < 2; kk++) {
      int kb = ((kk << 2) + q) << 3;
      bf16x8 af = *(const bf16x8*)(As + (((wv << 4) + rr) << 6) + kb);
#pragma unroll
      for (int ni = 0; ni < 6; ni++) {
        bf16x8 bfr = *(const bf16x8*)(Bs + (((ni << 4) + rr) << 6) + kb);
        acc[ni] = __builtin_amdgcn_mfma_f32_16x16x32_bf16(af, bfr, acc[ni], 0, 0, 0);
      }
    }
    __syncthreads();
  }

#pragma unroll
  for (int ni = 0; ni < 6; ni++) {
#pragma unroll
    for (int v = 0; v < 4; v++) {
      int row = rb + (wv << 4) + (q << 2) + v;
      int col = (ni << 4) + rr;
      Pout[(size_t)row * N2DIM + col] = acc[ni][v];
    }
  }
}

// ---------------- K3: sum partials, select leaf, add bias ------------------
__global__ __launch_bounds__(256) void k3_select(
    const float* __restrict__ P0, const float* __restrict__ P1,
    const float* __restrict__ bl2, const int* __restrict__ router,
    float* __restrict__ out) {
  int t = blockIdx.x * 256 + threadIdx.x;  // < 16384*12
  int b = t / 12, i4 = (t % 12) * 4;
  int sel = router[b];
  int cb = sel ? 48 : 0;
  int bb = sel ? 1488 : 0;
  float4 p0 = *(const float4*)(P0 + (size_t)b * N2DIM + cb + i4);
  float4 p1 = *(const float4*)(P1 + (size_t)b * N2DIM + cb + i4);
  float4 bz = *(const float4*)(bl2 + bb + i4);
  float4 r;
  r.x = p0.x + p1.x + bz.x;
  r.y = p0.y + p1.y + bz.y;
  r.z = p0.z + p1.z + bz.z;
  r.w = p0.w + p1.w + bz.w;
  *(float4*)(out + (size_t)b * 48 + i4) = r;
}

extern "C" void kernel_launch(void* const* d_in, const int* in_sizes, int n_in,
                              void* d_out, int out_size, void* d_ws, size_t ws_size,
                              hipStream_t stream) {
  const float* bd  = (const float*)d_in[0];
  const float* Wl1 = (const float*)d_in[1];
  const float* bl1 = (const float*)d_in[2];
  const float* Wl2 = (const float*)d_in[3];
  const float* bl2 = (const float*)d_in[4];
  const float* Wb1 = (const float*)d_in[5];
  const float* bb1 = (const float*)d_in[6];
  const float* Wb2 = (const float*)d_in[7];
  const float* bb2 = (const float*)d_in[8];

  char* ws = (char*)d_ws;
  ushort* x2bf  = (ushort*)(ws);                  // 16384*256*2  = 8,388,608
  ushort* wl1t  = (ushort*)(ws + 8388608);        // 2048*256*2   = 1,048,576
  ushort* w2t   = (ushort*)(ws + 9437184);        // 96*2048*2    =   393,216
  ushort* hl    = (ushort*)(ws + 9830400);        // 16384*2048*2 = 67,108,864
  float*  P     = (float*)(ws + 76939264);        // 2*16384*96*4 = 12,582,912
  int*    router= (int*)(ws + 89522176);          // 16384*4      =    65,536
  ushort* wb1t  = (ushort*)(ws + 89587712);       // 512*128*2    =   131,072
  float*  part  = (float*)(ws + 89718784);        // 8*16384*4    =   524,288
  int*    list  = (int*)(ws + 90243072);          // 16384*4      =    65,536
  int*    counter=(int*)(ws + 90308608);          // 4
  float*  outp  = (float*)d_out;

  k0_convert<<<dim3(16384), dim3(256), 0, stream>>>(bd, Wl1, Wl2, Wb1,
                                                    x2bf, wl1t, w2t, wb1t);
  hipMemsetAsync(counter, 0, 4, stream);
  k1a_score<<<dim3(4, 128), dim3(256), 0, stream>>>(x2bf, wb1t, bb1, Wb2, part);
  k1b_classify<<<dim3(64), dim3(256), 0, stream>>>(part, bb2, router, list, counter);
  k1c_recheck<<<dim3(128), dim3(256), 0, stream>>>(bd, Wb1, Wb2, bb1, bb2,
                                                   list, counter, router);
  k2_gemm1<<<dim3(16, 128), dim3(256), 0, stream>>>(x2bf, wl1t, bl1, hl);
  k2b_gemm2<<<dim3(2, 256), dim3(256), 0, stream>>>(hl, w2t, P);
  k3_select<<<dim3(768), dim3(256), 0, stream>>>(P, P + (size_t)NROWS * N2DIM, bl2,
                                                 router, outp);
}